// Round 1
// baseline (12178.202 us; speedup 1.0000x reference)
//
#include <hip/hip_runtime.h>

// ---------------- problem constants ----------------
constexpr int N  = 325;   // nodes
constexpr int B  = 64;    // batch
constexpr int T  = 12;    // encoder steps
constexpr int HZ = 12;    // decoder horizon
constexpr int U  = 64;    // rnn units
constexpr int BN = B * N; // 20800 rows
constexpr int FC = 16;    // feature chunk per diffusion block
constexpr int ELLW = 352; // ELL capacity >= N, can never overflow

constexpr int GRID = 256; // persistent blocks (1 per CU -> co-residency safe)
constexpr int BLK  = 512; // threads per block (8 waves)

typedef __attribute__((ext_vector_type(8))) short short8;
typedef __attribute__((ext_vector_type(4))) float floatx4;

// bf16 round-to-nearest-even + hi/lo split helpers
__device__ inline unsigned short f2bf(float f) {
    unsigned u = __float_as_uint(f);
    u += 0x7fff + ((u >> 16) & 1);
    return (unsigned short)(u >> 16);
}
__device__ inline unsigned pack_hilo(float v) {
    const unsigned short hi = f2bf(v);
    const float hif = __uint_as_float(((unsigned)hi) << 16);
    const unsigned short lo = f2bf(v - hif);
    return (unsigned)hi | ((unsigned)lo << 16);
}

// ---------------- setup kernels (unchanged) ----------------

__global__ void zero_kernel(float* __restrict__ p, int n) {
    int i = blockIdx.x * blockDim.x + threadIdx.x;
    const int stride = gridDim.x * blockDim.x;
    for (; i < n; i += stride) p[i] = 0.f;
}

// Build ELL (column-major, interleaved val/col) from dense S. One wave per row.
__global__ __launch_bounds__(64)
void ell_build(const float* __restrict__ S, float2* __restrict__ ellcv,
               int* __restrict__ nnz)
{
    const int m    = blockIdx.x;
    const int lane = threadIdx.x;
    const float* __restrict__ row = S + m * N;
    int count = 0;
    for (int base = 0; base < N; base += 64) {
        const int n = base + lane;
        const float v = (n < N) ? row[n] : 0.f;
        const unsigned long long mask = __ballot(v != 0.f);
        const int pre = __popcll(mask & ((1ull << lane) - 1ull));
        if (v != 0.f) {
            const int pos = count + pre;   // pos < N <= ELLW always
            ellcv[pos * N + m] = make_float2(v, __int_as_float(n));
        }
        count += __popcll(mask);
    }
    if (lane == 0) nnz[m] = count;
}

// Pre-pack a weight matrix (K3 x Nout, row-major fp32) into MFMA B-fragment
// order, split into bf16 hi/lo. Fragment: B[k=(lane>>4)*8+j][n*16+(lane&15)],
// stored as short8 at ((kc*NT+n)*64+lane). Zero-padded to K3p.
__global__ __launch_bounds__(64)
void prepack_w(const float* __restrict__ W, short* __restrict__ Wh,
               short* __restrict__ Wl, int K3, int Nout, int NT)
{
    const int kc = blockIdx.x, n = blockIdx.y, lane = threadIdx.x;
    const int quad = lane >> 4, l15 = lane & 15;
    short8 hv, lv;
    #pragma unroll
    for (int j = 0; j < 8; ++j) {
        const int k   = kc * 32 + quad * 8 + j;
        const int col = n * 16 + l15;
        const float w = (k < K3) ? W[k * Nout + col] : 0.f;
        const unsigned short h = f2bf(w);
        const float hf = __uint_as_float(((unsigned)h) << 16);
        hv[j] = (short)h;
        lv[j] = (short)f2bf(w - hf);
    }
    const size_t off = ((size_t)(kc * NT + n) * 64 + lane);
    ((short8*)Wh)[off] = hv;
    ((short8*)Wl)[off] = lv;
}

// ---------------- persistent mega-kernel ----------------

struct MegaParams {
    const float2* ellcv;
    const int*    nnz;
    const float*  inputs;
    float* h0; float* h1; float* dec_in;
    float* ru; unsigned* zcat;
    const short* Wgh[4]; const short* Wgl[4];
    const short* Wch[4]; const short* Wcl[4];
    const float* gb[4];  const float* cb[4];
    const float* pW; const float* pb;
    float* out;
    unsigned* bar;   // [0]=arrive count, [1]=generation
};

// grid-wide sense barrier; device-scope atomics so it is valid across XCDs.
__device__ __forceinline__ void gsync(unsigned* bar) {
    __syncthreads();
    if (threadIdx.x == 0) {
        __threadfence();   // release: make this block's writes visible device-wide
        const unsigned g = __hip_atomic_load(&bar[1], __ATOMIC_RELAXED,
                                             __HIP_MEMORY_SCOPE_AGENT);
        if (__hip_atomic_fetch_add(&bar[0], 1u, __ATOMIC_ACQ_REL,
                                   __HIP_MEMORY_SCOPE_AGENT) == (unsigned)(GRID - 1)) {
            __hip_atomic_store(&bar[0], 0u, __ATOMIC_RELAXED, __HIP_MEMORY_SCOPE_AGENT);
            __hip_atomic_store(&bar[1], g + 1u, __ATOMIC_RELEASE, __HIP_MEMORY_SCOPE_AGENT);
        } else {
            while (__hip_atomic_load(&bar[1], __ATOMIC_RELAXED,
                                     __HIP_MEMORY_SCOPE_AGENT) == g)
                __builtin_amdgcn_s_sleep(2);
        }
        __threadfence();   // acquire: invalidate stale L1 before reading others' data
    }
    __syncthreads();
}

// Sparse Chebyshev diffusion phase. Unit = (batch b, 16-feature chunk).
// Writes concatenated z = [z0|z1|z2] packed ushort2(bf16 hi, bf16 lo).
template<int DIN, int K3P, bool RMUL>
__device__ __forceinline__ void phaseZ(const float2* __restrict__ ellcv,
    const int* __restrict__ nnz, const float* __restrict__ x,
    const float* __restrict__ h, const float* __restrict__ ru,
    unsigned* __restrict__ zcat, float* __restrict__ s0, float* __restrict__ s1)
{
    constexpr int F   = DIN + U;
    constexpr int NCH = (F + FC - 1) / FC;
    constexpr int UNITS = 64 * NCH;
    const int tid = threadIdx.x;
    const int fg  = (tid & 3) * 4;   // feature sub-offset {0,4,8,12}
    const int mi  = tid >> 2;        // 0..127 output rows in parallel

    for (int u = blockIdx.x; u < UNITS; u += GRID) {
        const int b   = u / NCH;
        const int fc0 = (u - b * NCH) * FC;
        __syncthreads();  // protect LDS reuse from previous unit/phase

        // phase 1: concat(x, h or r*h) slice -> LDS, also write z0 part of zcat
        for (int idx = tid; idx < N * FC; idx += BLK) {
            const int n  = idx >> 4;
            const int f  = idx & 15;
            const int gf = fc0 + f;
            float v = 0.f;
            if (gf < F) {
                const int row = b * N + n;
                if (gf < DIN) {
                    v = x[(size_t)row * DIN + gf];
                } else {
                    v = h[(size_t)row * U + (gf - DIN)];
                    if (RMUL) v *= ru[(size_t)row * 128 + (gf - DIN)]; // r = ru[:, :64]
                }
                // x-part of z0 is identical to the gate pass -> skip rewrite
                if (!(RMUL && gf < DIN))
                    zcat[(size_t)row * K3P + gf] = pack_hilo(v);
            }
            s0[idx] = v;
        }
        // zero the K-padding strip [3F, K3P) (chunk-0 blocks)
        if constexpr (K3P > 3 * F) {
            if (fc0 == 0) {
                constexpr int PAD = K3P - 3 * F;
                for (int idx = tid; idx < N * PAD; idx += BLK) {
                    const int n = idx / PAD;
                    const int c = idx - n * PAD;
                    zcat[(size_t)(b * N + n) * K3P + 3 * F + c] = 0u;
                }
            }
        }
        __syncthreads();

        // phase 2: s1 = S @ s0 (sparse)
        for (int pass = 0; pass < 3; ++pass) {
            const int m = pass * 128 + mi;
            if (m < N) {
                const int cnt = nnz[m];
                float a0 = 0.f, a1 = 0.f, a2 = 0.f, a3 = 0.f;
                #pragma unroll 4
                for (int j = 0; j < cnt; ++j) {
                    const float2 cv = ellcv[j * N + m];
                    const int col = __float_as_int(cv.y);
                    const float4 v = *(const float4*)&s0[col * FC + fg];
                    a0 += cv.x * v.x; a1 += cv.x * v.y;
                    a2 += cv.x * v.z; a3 += cv.x * v.w;
                }
                *(float4*)&s1[m * FC + fg] = make_float4(a0, a1, a2, a3);
                const int row = b * N + m;
                float vals[4] = {a0, a1, a2, a3};
                #pragma unroll
                for (int j = 0; j < 4; ++j) {
                    const int gf = fc0 + fg + j;
                    if (gf < F) zcat[(size_t)row * K3P + F + gf] = pack_hilo(vals[j]);
                }
            }
        }
        __syncthreads();

        // phase 3: z2 = 2 * S @ s1 - s0 (sparse)
        for (int pass = 0; pass < 3; ++pass) {
            const int m = pass * 128 + mi;
            if (m < N) {
                const int cnt = nnz[m];
                float a0 = 0.f, a1 = 0.f, a2 = 0.f, a3 = 0.f;
                #pragma unroll 4
                for (int j = 0; j < cnt; ++j) {
                    const float2 cv = ellcv[j * N + m];
                    const int col = __float_as_int(cv.y);
                    const float4 v = *(const float4*)&s1[col * FC + fg];
                    a0 += cv.x * v.x; a1 += cv.x * v.y;
                    a2 += cv.x * v.z; a3 += cv.x * v.w;
                }
                const int row = b * N + m;
                float vals[4] = {a0, a1, a2, a3};
                #pragma unroll
                for (int j = 0; j < 4; ++j) {
                    const int gf = fc0 + fg + j;
                    if (gf < F)
                        zcat[(size_t)row * K3P + 2 * F + gf] =
                            pack_hilo(2.f * vals[j] - s0[m * FC + fg + j]);
                }
            }
        }
    }
}

// Gate MFMA phase: ru = sigmoid(zcat @ W + b). Unit = 128 rows (8 waves x 16).
template<int K3P>
__device__ __forceinline__ void phaseG(const unsigned* __restrict__ zcat,
    const short8* __restrict__ Wh, const short8* __restrict__ Wl,
    const float* __restrict__ bias, float* __restrict__ ru)
{
    constexpr int NT = 8, KC = K3P >> 5;
    constexpr int UNITS = (BN + 127) / 128;
    const int tid = threadIdx.x, wave = tid >> 6, lane = tid & 63;
    const int quad = lane >> 4, l15 = lane & 15;

    for (int u = blockIdx.x; u < UNITS; u += GRID) {
        const int row0 = u * 128 + wave * 16;
        if (row0 >= BN) continue;   // wave-uniform guard, no barriers inside
        floatx4 acc[NT];
        #pragma unroll
        for (int n = 0; n < NT; ++n) {
            const float bv = bias[n * 16 + l15];
            acc[n] = (floatx4){bv, bv, bv, bv};
        }
        const unsigned* __restrict__ zrow = zcat + (size_t)(row0 + l15) * K3P + quad * 8;
        for (int kc = 0; kc < KC; ++kc) {
            const uint4* p = (const uint4*)(zrow + kc * 32);
            const uint4 u0 = p[0], u1 = p[1];
            const unsigned uu[8] = {u0.x, u0.y, u0.z, u0.w, u1.x, u1.y, u1.z, u1.w};
            short8 ahi, alo;
            #pragma unroll
            for (int j = 0; j < 8; ++j) {
                ahi[j] = (short)(uu[j] & 0xffffu);
                alo[j] = (short)(uu[j] >> 16);
            }
            const short8* __restrict__ wh = Wh + (size_t)(kc * NT) * 64 + lane;
            const short8* __restrict__ wl = Wl + (size_t)(kc * NT) * 64 + lane;
            #pragma unroll
            for (int n = 0; n < NT; ++n) {
                const short8 bh = wh[n * 64], bl = wl[n * 64];
                acc[n] = __builtin_amdgcn_mfma_f32_16x16x32_bf16(ahi, bh, acc[n], 0, 0, 0);
                acc[n] = __builtin_amdgcn_mfma_f32_16x16x32_bf16(ahi, bl, acc[n], 0, 0, 0);
                acc[n] = __builtin_amdgcn_mfma_f32_16x16x32_bf16(alo, bh, acc[n], 0, 0, 0);
            }
        }
        #pragma unroll
        for (int n = 0; n < NT; ++n) {
            const int col = n * 16 + l15;
            #pragma unroll
            for (int r = 0; r < 4; ++r) {
                const int row = row0 + quad * 4 + r;   // C/D: row=(lane>>4)*4+reg
                ru[(size_t)row * 128 + col] = 1.f / (1.f + __expf(-acc[n][r]));
            }
        }
    }
}

// Candidate MFMA phase: c = tanh(zcat @ W + b); h = u*h + (1-u)*c.
// For PROJ (decoder layer 1): fused out = h . pW + pb, also feeds dec_in.
template<int K3P, bool PROJ>
__device__ __forceinline__ void phaseC(const unsigned* __restrict__ zcat,
    const short8* __restrict__ Wh, const short8* __restrict__ Wl,
    const float* __restrict__ bias, const float* __restrict__ ru,
    float* __restrict__ h, const float* __restrict__ pW,
    const float* __restrict__ pb, float* __restrict__ outp,
    float* __restrict__ dec_in)
{
    constexpr int NT = 4, KC = K3P >> 5;
    constexpr int UNITS = (BN + 127) / 128;
    const int tid = threadIdx.x, wave = tid >> 6, lane = tid & 63;
    const int quad = lane >> 4, l15 = lane & 15;

    for (int u = blockIdx.x; u < UNITS; u += GRID) {
        const int row0 = u * 128 + wave * 16;
        if (row0 >= BN) continue;
        floatx4 acc[NT];
        #pragma unroll
        for (int n = 0; n < NT; ++n) {
            const float bv = bias[n * 16 + l15];
            acc[n] = (floatx4){bv, bv, bv, bv};
        }
        const unsigned* __restrict__ zrow = zcat + (size_t)(row0 + l15) * K3P + quad * 8;
        for (int kc = 0; kc < KC; ++kc) {
            const uint4* p = (const uint4*)(zrow + kc * 32);
            const uint4 u0 = p[0], u1 = p[1];
            const unsigned uu[8] = {u0.x, u0.y, u0.z, u0.w, u1.x, u1.y, u1.z, u1.w};
            short8 ahi, alo;
            #pragma unroll
            for (int j = 0; j < 8; ++j) {
                ahi[j] = (short)(uu[j] & 0xffffu);
                alo[j] = (short)(uu[j] >> 16);
            }
            const short8* __restrict__ wh = Wh + (size_t)(kc * NT) * 64 + lane;
            const short8* __restrict__ wl = Wl + (size_t)(kc * NT) * 64 + lane;
            #pragma unroll
            for (int n = 0; n < NT; ++n) {
                const short8 bh = wh[n * 64], bl = wl[n * 64];
                acc[n] = __builtin_amdgcn_mfma_f32_16x16x32_bf16(ahi, bh, acc[n], 0, 0, 0);
                acc[n] = __builtin_amdgcn_mfma_f32_16x16x32_bf16(ahi, bl, acc[n], 0, 0, 0);
                acc[n] = __builtin_amdgcn_mfma_f32_16x16x32_bf16(alo, bh, acc[n], 0, 0, 0);
            }
        }
        float pr[4] = {0.f, 0.f, 0.f, 0.f};
        #pragma unroll
        for (int n = 0; n < NT; ++n) {
            const int col = n * 16 + l15;
            float pw = 0.f;
            if constexpr (PROJ) pw = pW[col];
            #pragma unroll
            for (int r = 0; r < 4; ++r) {
                const int row = row0 + quad * 4 + r;
                const float c  = tanhf(acc[n][r]);
                const float ug = ru[(size_t)row * 128 + 64 + col];  // u = ru[:, 64:]
                const float hv = h[(size_t)row * 64 + col];
                const float hn = ug * hv + (1.f - ug) * c;
                h[(size_t)row * 64 + col] = hn;
                if constexpr (PROJ) pr[r] += hn * pw;
            }
        }
        if constexpr (PROJ) {
            #pragma unroll
            for (int r = 0; r < 4; ++r) {
                float v = pr[r];
                v += __shfl_xor(v, 1); v += __shfl_xor(v, 2);
                v += __shfl_xor(v, 4); v += __shfl_xor(v, 8);
                if (l15 == 0) {
                    const int row = row0 + quad * 4 + r;
                    const float o = v + pb[0];
                    outp[row]   = o;
                    dec_in[row] = o;
                }
            }
        }
    }
}

__global__ __launch_bounds__(BLK, 2)
void mega_kernel(MegaParams P)
{
    __shared__ __align__(16) float s0[N * FC];
    __shared__ __align__(16) float s1[N * FC];

    // -------- encoder --------
    for (int t = 0; t < T; ++t) {
        const float* x = P.inputs + (size_t)t * BN * 2;
        // layer 0 (din=2, K3p=224)
        phaseZ<2, 224, false>(P.ellcv, P.nnz, x, P.h0, P.ru, P.zcat, s0, s1);
        gsync(P.bar);
        phaseG<224>(P.zcat, (const short8*)P.Wgh[0], (const short8*)P.Wgl[0], P.gb[0], P.ru);
        gsync(P.bar);
        phaseZ<2, 224, true>(P.ellcv, P.nnz, x, P.h0, P.ru, P.zcat, s0, s1);
        gsync(P.bar);
        phaseC<224, false>(P.zcat, (const short8*)P.Wch[0], (const short8*)P.Wcl[0],
                           P.cb[0], P.ru, P.h0, nullptr, nullptr, nullptr, nullptr);
        gsync(P.bar);
        // layer 1 (din=64, K3p=384)
        phaseZ<64, 384, false>(P.ellcv, P.nnz, P.h0, P.h1, P.ru, P.zcat, s0, s1);
        gsync(P.bar);
        phaseG<384>(P.zcat, (const short8*)P.Wgh[1], (const short8*)P.Wgl[1], P.gb[1], P.ru);
        gsync(P.bar);
        phaseZ<64, 384, true>(P.ellcv, P.nnz, P.h0, P.h1, P.ru, P.zcat, s0, s1);
        gsync(P.bar);
        phaseC<384, false>(P.zcat, (const short8*)P.Wch[1], (const short8*)P.Wcl[1],
                           P.cb[1], P.ru, P.h1, nullptr, nullptr, nullptr, nullptr);
        gsync(P.bar);
    }
    // -------- decoder --------
    for (int hz = 0; hz < HZ; ++hz) {
        // layer 0 (din=1, K3p=224)
        phaseZ<1, 224, false>(P.ellcv, P.nnz, P.dec_in, P.h0, P.ru, P.zcat, s0, s1);
        gsync(P.bar);
        phaseG<224>(P.zcat, (const short8*)P.Wgh[2], (const short8*)P.Wgl[2], P.gb[2], P.ru);
        gsync(P.bar);
        phaseZ<1, 224, true>(P.ellcv, P.nnz, P.dec_in, P.h0, P.ru, P.zcat, s0, s1);
        gsync(P.bar);
        phaseC<224, false>(P.zcat, (const short8*)P.Wch[2], (const short8*)P.Wcl[2],
                           P.cb[2], P.ru, P.h0, nullptr, nullptr, nullptr, nullptr);
        gsync(P.bar);
        // layer 1 (din=64, K3p=384) + fused projection
        phaseZ<64, 384, false>(P.ellcv, P.nnz, P.h0, P.h1, P.ru, P.zcat, s0, s1);
        gsync(P.bar);
        phaseG<384>(P.zcat, (const short8*)P.Wgh[3], (const short8*)P.Wgl[3], P.gb[3], P.ru);
        gsync(P.bar);
        phaseZ<64, 384, true>(P.ellcv, P.nnz, P.h0, P.h1, P.ru, P.zcat, s0, s1);
        gsync(P.bar);
        phaseC<384, true>(P.zcat, (const short8*)P.Wch[3], (const short8*)P.Wcl[3],
                          P.cb[3], P.ru, P.h1, P.pW, P.pb,
                          P.out + (size_t)hz * BN, P.dec_in);
        gsync(P.bar);
    }
}

// ---------------- host launcher ----------------

extern "C" void kernel_launch(void* const* d_in, const int* in_sizes, int n_in,
                              void* d_out, int out_size, void* d_ws, size_t ws_size,
                              hipStream_t stream)
{
    const float* inputs = (const float*)d_in[0];
    const float* S      = (const float*)d_in[1];
    const float* Wt[4][4];
    for (int l = 0; l < 4; ++l)
        for (int j = 0; j < 4; ++j)
            Wt[l][j] = (const float*)d_in[2 + l * 4 + j];
    const float* pW = (const float*)d_in[18];
    const float* pb = (const float*)d_in[19];
    float* out = (float*)d_out;

    // workspace layout (identical to previous version; barrier appended at end)
    float*    ws     = (float*)d_ws;
    float*    h0     = ws;                       // BN*U
    float*    h1     = h0 + BN * U;              // BN*U
    float*    dec_in = h1 + BN * U;              // BN
    float*    ru     = dec_in + BN;              // BN*128
    unsigned* zcat   = (unsigned*)(ru + BN * 128);   // BN*384 (16B aligned)
    float2*   ellcv  = (float2*)(zcat + (size_t)BN * 384);
    int*      nnz    = (int*)(ellcv + (size_t)ELLW * N);
    char*     wpbase = (char*)(nnz + ((N + 3) & ~3));
    wpbase = (char*)(((uintptr_t)wpbase + 15) & ~(uintptr_t)15);

    // layer geometry: K3, K3p (pad to 32)
    const int K3s[4]  = {198, 384, 195, 384};
    const int K3ps[4] = {224, 384, 224, 384};
    short *Wgh[4], *Wgl[4], *Wch[4], *Wcl[4];
    size_t off = 0;
    for (int l = 0; l < 4; ++l) {
        const size_t ge = (size_t)K3ps[l] * 128, ce = (size_t)K3ps[l] * 64;
        Wgh[l] = (short*)(wpbase + off); off += ge * 2;
        Wgl[l] = (short*)(wpbase + off); off += ge * 2;
        Wch[l] = (short*)(wpbase + off); off += ce * 2;
        Wcl[l] = (short*)(wpbase + off); off += ce * 2;
    }
    unsigned* bar = (unsigned*)(wpbase + ((off + 15) & ~(size_t)15));  // 4 u32

    zero_kernel<<<1024, 256, 0, stream>>>(h0, 2 * BN * U + BN);
    zero_kernel<<<1, 64, 0, stream>>>((float*)bar, 4);
    ell_build<<<N, 64, 0, stream>>>(S, ellcv, nnz);
    for (int l = 0; l < 4; ++l) {
        prepack_w<<<dim3(K3ps[l] / 32, 8), 64, 0, stream>>>(Wt[l][0], Wgh[l], Wgl[l],
                                                            K3s[l], 128, 8);
        prepack_w<<<dim3(K3ps[l] / 32, 4), 64, 0, stream>>>(Wt[l][2], Wch[l], Wcl[l],
                                                            K3s[l], 64, 4);
    }

    MegaParams P;
    P.ellcv = ellcv; P.nnz = nnz; P.inputs = inputs;
    P.h0 = h0; P.h1 = h1; P.dec_in = dec_in; P.ru = ru; P.zcat = zcat;
    for (int l = 0; l < 4; ++l) {
        P.Wgh[l] = Wgh[l]; P.Wgl[l] = Wgl[l];
        P.Wch[l] = Wch[l]; P.Wcl[l] = Wcl[l];
        P.gb[l] = Wt[l][1]; P.cb[l] = Wt[l][3];
    }
    P.pW = pW; P.pb = pb; P.out = out; P.bar = bar;

    mega_kernel<<<GRID, BLK, 0, stream>>>(P);
}